// Round 1
// baseline (1398.325 us; speedup 1.0000x reference)
//
#include <hip/hip_runtime.h>
#include <hip/hip_bf16.h>
#include <math.h>

#define NNODES 50000
#define NEDGES 800000
#define NGRAPH 64
#define FIN 128
#define HC 256     // H * HID
#define NHEAD 4
#define NOUT 10
#define ETOT (NEDGES + NNODES)   // edges + self-loops

// ---------------- counting sort of edges by dst ----------------

__global__ void degree_kernel(const int* __restrict__ ei, int* __restrict__ deg) {
    int e = blockIdx.x * blockDim.x + threadIdx.x;
    if (e >= ETOT) return;
    int dst = (e < NEDGES) ? ei[NEDGES + e] : (e - NEDGES);
    atomicAdd(&deg[dst], 1);
}

__global__ __launch_bounds__(1024) void scan_kernel(const int* __restrict__ deg,
                                                    int* __restrict__ off) {
    __shared__ int wsum[16];
    int tid = threadIdx.x, lane = tid & 63, wid = tid >> 6;
    int carry = 0;
    for (int base = 0; base < NNODES; base += 1024) {
        int i = base + tid;
        int v = (i < NNODES) ? deg[i] : 0;
        int x = v;
        #pragma unroll
        for (int o = 1; o < 64; o <<= 1) {
            int t = __shfl_up(x, o);
            if (lane >= o) x += t;
        }
        if (lane == 63) wsum[wid] = x;
        __syncthreads();
        if (wid == 0 && lane < 16) {
            int w = wsum[lane];
            #pragma unroll
            for (int o = 1; o < 16; o <<= 1) {
                int t = __shfl_up(w, o, 16);
                if (lane >= o) w += t;
            }
            wsum[lane] = w;
        }
        __syncthreads();
        int wexcl = (wid == 0) ? 0 : wsum[wid - 1];
        if (i < NNODES) off[i] = carry + wexcl + (x - v);
        int total = wsum[15];
        __syncthreads();
        carry += total;
    }
    if (tid == 0) off[NNODES] = carry;
}

__global__ void scatter_kernel(const int* __restrict__ ei, const int* __restrict__ off,
                               int* __restrict__ cur, int* __restrict__ ssrc) {
    int e = blockIdx.x * blockDim.x + threadIdx.x;
    if (e >= ETOT) return;
    int src, dst;
    if (e < NEDGES) { src = ei[e]; dst = ei[NEDGES + e]; }
    else            { src = dst = e - NEDGES; }
    int pos = off[dst] + atomicAdd(&cur[dst], 1);
    ssrc[pos] = src;
}

// ---------------- fp32 tiled GEMM: C[N,256] = A[N,K] @ B[256,K]^T ----------------

#define BM 64
#define BN 64
#define BK 16
__global__ __launch_bounds__(256) void gemm_nt(const float* __restrict__ A,
                                               const float* __restrict__ B,
                                               float* __restrict__ C, int K) {
    __shared__ float As[BK][BM + 4];
    __shared__ float Bs[BK][BN + 4];
    int tid = threadIdx.x;
    int brow = blockIdx.x * BM, bcol = blockIdx.y * BN;
    int lr = tid >> 2;            // 0..63
    int lc = (tid & 3) * 4;       // 0,4,8,12
    int ty = tid >> 4, tx = tid & 15;
    float acc[4][4] = {};
    for (int k0 = 0; k0 < K; k0 += BK) {
        float4 av = make_float4(0.f, 0.f, 0.f, 0.f);
        int ar = brow + lr;
        if (ar < NNODES) av = *(const float4*)(A + (size_t)ar * K + k0 + lc);
        float4 bv = *(const float4*)(B + (size_t)(bcol + lr) * K + k0 + lc);
        __syncthreads();
        As[lc + 0][lr] = av.x; As[lc + 1][lr] = av.y; As[lc + 2][lr] = av.z; As[lc + 3][lr] = av.w;
        Bs[lc + 0][lr] = bv.x; Bs[lc + 1][lr] = bv.y; Bs[lc + 2][lr] = bv.z; Bs[lc + 3][lr] = bv.w;
        __syncthreads();
        #pragma unroll
        for (int kk = 0; kk < BK; ++kk) {
            float4 a4 = *(const float4*)(&As[kk][ty * 4]);
            float4 b4 = *(const float4*)(&Bs[kk][tx * 4]);
            float a[4] = {a4.x, a4.y, a4.z, a4.w};
            float b[4] = {b4.x, b4.y, b4.z, b4.w};
            #pragma unroll
            for (int i = 0; i < 4; ++i)
                #pragma unroll
                for (int j = 0; j < 4; ++j)
                    acc[i][j] = fmaf(a[i], b[j], acc[i][j]);
        }
    }
    #pragma unroll
    for (int i = 0; i < 4; ++i) {
        int r = brow + ty * 4 + i;
        if (r < NNODES) {
            float4 o = make_float4(acc[i][0], acc[i][1], acc[i][2], acc[i][3]);
            *(float4*)(C + (size_t)r * HC + bcol + tx * 4) = o;
        }
    }
}

// ---------------- per-node attention scalars e_src/e_dst ----------------

__global__ __launch_bounds__(256) void compute_e_kernel(const float* __restrict__ h,
                                                        const float* __restrict__ asrc,
                                                        const float* __restrict__ adst,
                                                        float* __restrict__ es,
                                                        float* __restrict__ ed) {
    int node = blockIdx.x * 4 + (threadIdx.x >> 6);
    if (node >= NNODES) return;
    int lane = threadIdx.x & 63;
    float4 hv = *(const float4*)(h + (size_t)node * HC + lane * 4);
    float4 a1 = *(const float4*)(asrc + lane * 4);
    float4 a2 = *(const float4*)(adst + lane * 4);
    float ps = hv.x * a1.x + hv.y * a1.y + hv.z * a1.z + hv.w * a1.w;
    float pd = hv.x * a2.x + hv.y * a2.y + hv.z * a2.z + hv.w * a2.w;
    #pragma unroll
    for (int o = 8; o > 0; o >>= 1) {   // reduce within each 16-lane head group
        ps += __shfl_down(ps, o, 16);
        pd += __shfl_down(pd, o, 16);
    }
    if ((lane & 15) == 0) {
        es[node * 4 + (lane >> 4)] = ps;
        ed[node * 4 + (lane >> 4)] = pd;
    }
}

// ---------------- one wave per dst node: softmax + weighted gather + bias (+elu) ----------------

__global__ __launch_bounds__(64) void aggregate_kernel(const float* __restrict__ h,
                                                       const int* __restrict__ ssrc,
                                                       const int* __restrict__ off,
                                                       const float* __restrict__ es,
                                                       const float* __restrict__ ed,
                                                       const float* __restrict__ bias,
                                                       float* __restrict__ out,
                                                       int apply_elu) {
    int dst = blockIdx.x;
    int lane = threadIdx.x;
    int s = off[dst], e = off[dst + 1];
    float4 ed4 = *(const float4*)(ed + dst * 4);
    // phase 1: per-head max logit over all incoming edges
    float m0 = -1e30f, m1 = -1e30f, m2 = -1e30f, m3 = -1e30f;
    for (int p = s + lane; p < e; p += 64) {
        int src = ssrc[p];
        float4 es4 = *(const float4*)(es + src * 4);
        float l0 = es4.x + ed4.x; l0 = l0 > 0.f ? l0 : 0.2f * l0;
        float l1 = es4.y + ed4.y; l1 = l1 > 0.f ? l1 : 0.2f * l1;
        float l2 = es4.z + ed4.z; l2 = l2 > 0.f ? l2 : 0.2f * l2;
        float l3 = es4.w + ed4.w; l3 = l3 > 0.f ? l3 : 0.2f * l3;
        m0 = fmaxf(m0, l0); m1 = fmaxf(m1, l1); m2 = fmaxf(m2, l2); m3 = fmaxf(m3, l3);
    }
    #pragma unroll
    for (int o = 32; o > 0; o >>= 1) {
        m0 = fmaxf(m0, __shfl_xor(m0, o));
        m1 = fmaxf(m1, __shfl_xor(m1, o));
        m2 = fmaxf(m2, __shfl_xor(m2, o));
        m3 = fmaxf(m3, __shfl_xor(m3, o));
    }
    int head = lane >> 4;
    float myM = (head == 0) ? m0 : (head == 1) ? m1 : (head == 2) ? m2 : m3;
    float edh = (head == 0) ? ed4.x : (head == 1) ? ed4.y : (head == 2) ? ed4.z : ed4.w;
    // phase 2: weighted sum over edges; lane owns channels [lane*4, lane*4+4)
    float denom = 0.f;
    float4 acc = make_float4(0.f, 0.f, 0.f, 0.f);
    for (int p = s; p < e; ++p) {
        int src = ssrc[p];
        float l = es[src * 4 + head] + edh;
        l = l > 0.f ? l : 0.2f * l;
        float ex = __expf(l - myM);
        denom += ex;
        float4 hv = *(const float4*)(h + (size_t)src * HC + lane * 4);
        acc.x += hv.x * ex; acc.y += hv.y * ex; acc.z += hv.z * ex; acc.w += hv.w * ex;
    }
    float inv = 1.f / (denom + 1e-16f);
    float4 b4 = *(const float4*)(bias + lane * 4);
    float o0 = acc.x * inv + b4.x;
    float o1 = acc.y * inv + b4.y;
    float o2 = acc.z * inv + b4.z;
    float o3 = acc.w * inv + b4.w;
    if (apply_elu) {
        o0 = o0 > 0.f ? o0 : expm1f(o0);
        o1 = o1 > 0.f ? o1 : expm1f(o1);
        o2 = o2 > 0.f ? o2 : expm1f(o2);
        o3 = o3 > 0.f ? o3 : expm1f(o3);
    }
    *(float4*)(out + (size_t)dst * HC + lane * 4) = make_float4(o0, o1, o2, o3);
}

// ---------------- global mean pool (atomics into [G,256]) ----------------

__global__ __launch_bounds__(256) void pool_kernel(const float* __restrict__ hin,
                                                   const int* __restrict__ batch,
                                                   float* __restrict__ pool,
                                                   int* __restrict__ cnt) {
    int node = blockIdx.x * 4 + (threadIdx.x >> 6);
    if (node >= NNODES) return;
    int lane = threadIdx.x & 63;
    int g = batch[node];
    float4 v = *(const float4*)(hin + (size_t)node * HC + lane * 4);
    float* p = pool + g * HC + lane * 4;
    atomicAdd(p + 0, v.x); atomicAdd(p + 1, v.y);
    atomicAdd(p + 2, v.z); atomicAdd(p + 3, v.w);
    if (lane == 0) atomicAdd(&cnt[g], 1);
}

// ---------------- final classifier: out[G,10] = (pool/cnt) @ Wl^T + bl ----------------

__global__ __launch_bounds__(64) void final_kernel(const float* __restrict__ pool,
                                                   const int* __restrict__ cnt,
                                                   const float* __restrict__ Wl,
                                                   const float* __restrict__ bl,
                                                   float* __restrict__ out) {
    int g = blockIdx.x;
    int lane = threadIdx.x;
    float4 pv = *(const float4*)(pool + g * HC + lane * 4);
    float acc[NOUT];
    #pragma unroll
    for (int o = 0; o < NOUT; ++o) {
        float4 wv = *(const float4*)(Wl + o * HC + lane * 4);
        acc[o] = pv.x * wv.x + pv.y * wv.y + pv.z * wv.z + pv.w * wv.w;
    }
    #pragma unroll
    for (int s = 32; s > 0; s >>= 1)
        #pragma unroll
        for (int o = 0; o < NOUT; ++o)
            acc[o] += __shfl_xor(acc[o], s);
    if (lane == 0) {
        float c = fmaxf((float)cnt[g], 1.0f);
        #pragma unroll
        for (int o = 0; o < NOUT; ++o)
            out[g * NOUT + o] = acc[o] / c + bl[o];
    }
}

// ---------------- launch ----------------

extern "C" void kernel_launch(void* const* d_in, const int* in_sizes, int n_in,
                              void* d_out, int out_size, void* d_ws, size_t ws_size,
                              hipStream_t stream) {
    (void)in_sizes; (void)n_in; (void)out_size; (void)ws_size;
    const float* x   = (const float*)d_in[0];
    const int*   ei  = (const int*)d_in[1];
    const int*   bat = (const int*)d_in[2];
    const float* W1  = (const float*)d_in[3];
    const float* as1 = (const float*)d_in[4];
    const float* ad1 = (const float*)d_in[5];
    const float* b1  = (const float*)d_in[6];
    const float* W2  = (const float*)d_in[7];
    const float* as2 = (const float*)d_in[8];
    const float* ad2 = (const float*)d_in[9];
    const float* b2  = (const float*)d_in[10];
    const float* W3  = (const float*)d_in[11];
    const float* as3 = (const float*)d_in[12];
    const float* ad3 = (const float*)d_in[13];
    const float* b3  = (const float*)d_in[14];
    const float* Wl  = (const float*)d_in[15];
    const float* bl  = (const float*)d_in[16];
    float* out = (float*)d_out;

    char* ws = (char*)d_ws;
    size_t p = 0;
    auto alloc = [&](size_t bytes) {
        size_t a = p;
        p += (bytes + 255) & ~(size_t)255;
        return a;
    };
    int*   off  = (int*)(ws + alloc((NNODES + 1) * 4));
    int*   deg  = (int*)(ws + alloc((size_t)NNODES * 4));
    int*   cur  = (int*)(ws + alloc((size_t)NNODES * 4));
    int*   ssrc = (int*)(ws + alloc((size_t)ETOT * 4));
    float* es   = (float*)(ws + alloc((size_t)NNODES * NHEAD * 4));
    float* ed   = (float*)(ws + alloc((size_t)NNODES * NHEAD * 4));
    float* B0v  = (float*)(ws + alloc((size_t)NNODES * HC * 4));
    float* B1v  = (float*)(ws + alloc((size_t)NNODES * HC * 4));
    float* pool = (float*)(ws + alloc((size_t)NGRAPH * HC * 4));
    int*   cnt  = (int*)(ws + alloc((size_t)NGRAPH * 4));

    // zero deg+cur (contiguous) and pool+cnt (contiguous)
    hipMemsetAsync(deg, 0, (size_t)((char*)ssrc - (char*)deg), stream);
    hipMemsetAsync(pool, 0, (size_t)((char*)cnt - (char*)pool) + NGRAPH * 4, stream);

    // counting sort of edges (incl. self-loops) by dst — reused by all 3 layers
    degree_kernel<<<(ETOT + 255) / 256, 256, 0, stream>>>(ei, deg);
    scan_kernel<<<1, 1024, 0, stream>>>(deg, off);
    scatter_kernel<<<(ETOT + 255) / 256, 256, 0, stream>>>(ei, off, cur, ssrc);

    dim3 ggrid((NNODES + BM - 1) / BM, HC / BN);
    int eblocks = (NNODES + 3) / 4;

    // layer 1
    gemm_nt<<<ggrid, 256, 0, stream>>>(x, W1, B0v, FIN);
    compute_e_kernel<<<eblocks, 256, 0, stream>>>(B0v, as1, ad1, es, ed);
    aggregate_kernel<<<NNODES, 64, 0, stream>>>(B0v, ssrc, off, es, ed, b1, B1v, 1);
    // layer 2
    gemm_nt<<<ggrid, 256, 0, stream>>>(B1v, W2, B0v, HC);
    compute_e_kernel<<<eblocks, 256, 0, stream>>>(B0v, as2, ad2, es, ed);
    aggregate_kernel<<<NNODES, 64, 0, stream>>>(B0v, ssrc, off, es, ed, b2, B1v, 1);
    // layer 3
    gemm_nt<<<ggrid, 256, 0, stream>>>(B1v, W3, B0v, HC);
    compute_e_kernel<<<eblocks, 256, 0, stream>>>(B0v, as3, ad3, es, ed);
    aggregate_kernel<<<NNODES, 64, 0, stream>>>(B0v, ssrc, off, es, ed, b3, B1v, 0);

    // pool + classify
    pool_kernel<<<eblocks, 256, 0, stream>>>(B1v, bat, pool, cnt);
    final_kernel<<<NGRAPH, 64, 0, stream>>>(pool, cnt, Wl, bl, out);
}

// Round 2
// 940.089 us; speedup vs baseline: 1.4874x; 1.4874x over previous
//
#include <hip/hip_runtime.h>
#include <hip/hip_bf16.h>
#include <math.h>

#define NNODES 50000
#define NEDGES 800000
#define NGRAPH 64
#define FIN 128
#define HC 256     // H * HID
#define NHEAD 4
#define NOUT 10
#define ETOT (NEDGES + NNODES)   // edges + self-loops

// ---------------- counting sort of edges by dst ----------------

__global__ void degree_kernel(const int* __restrict__ ei, int* __restrict__ deg) {
    int e = blockIdx.x * blockDim.x + threadIdx.x;
    if (e >= ETOT) return;
    int dst = (e < NEDGES) ? ei[NEDGES + e] : (e - NEDGES);
    atomicAdd(&deg[dst], 1);
}

__global__ __launch_bounds__(1024) void scan_kernel(const int* __restrict__ deg,
                                                    int* __restrict__ off) {
    __shared__ int wsum[16];
    int tid = threadIdx.x, lane = tid & 63, wid = tid >> 6;
    int carry = 0;
    for (int base = 0; base < NNODES; base += 1024) {
        int i = base + tid;
        int v = (i < NNODES) ? deg[i] : 0;
        int x = v;
        #pragma unroll
        for (int o = 1; o < 64; o <<= 1) {
            int t = __shfl_up(x, o);
            if (lane >= o) x += t;
        }
        if (lane == 63) wsum[wid] = x;
        __syncthreads();
        if (wid == 0 && lane < 16) {
            int w = wsum[lane];
            #pragma unroll
            for (int o = 1; o < 16; o <<= 1) {
                int t = __shfl_up(w, o, 16);
                if (lane >= o) w += t;
            }
            wsum[lane] = w;
        }
        __syncthreads();
        int wexcl = (wid == 0) ? 0 : wsum[wid - 1];
        if (i < NNODES) off[i] = carry + wexcl + (x - v);
        int total = wsum[15];
        __syncthreads();
        carry += total;
    }
    if (tid == 0) off[NNODES] = carry;
}

__global__ void scatter_kernel(const int* __restrict__ ei, const int* __restrict__ off,
                               int* __restrict__ cur, int* __restrict__ ssrc) {
    int e = blockIdx.x * blockDim.x + threadIdx.x;
    if (e >= ETOT) return;
    int src, dst;
    if (e < NEDGES) { src = ei[e]; dst = ei[NEDGES + e]; }
    else            { src = dst = e - NEDGES; }
    int pos = off[dst] + atomicAdd(&cur[dst], 1);
    ssrc[pos] = src;
}

// ---------------- fp32 tiled GEMM: C[N,256] = A[N,K] @ B[256,K]^T ----------------

#define BM 64
#define BN 64
#define BK 16
__global__ __launch_bounds__(256) void gemm_nt(const float* __restrict__ A,
                                               const float* __restrict__ B,
                                               float* __restrict__ C, int K) {
    __shared__ float As[BK][BM + 4];
    __shared__ float Bs[BK][BN + 4];
    int tid = threadIdx.x;
    int brow = blockIdx.x * BM, bcol = blockIdx.y * BN;
    int lr = tid >> 2;            // 0..63
    int lc = (tid & 3) * 4;       // 0,4,8,12
    int ty = tid >> 4, tx = tid & 15;
    float acc[4][4] = {};
    for (int k0 = 0; k0 < K; k0 += BK) {
        float4 av = make_float4(0.f, 0.f, 0.f, 0.f);
        int ar = brow + lr;
        if (ar < NNODES) av = *(const float4*)(A + (size_t)ar * K + k0 + lc);
        float4 bv = *(const float4*)(B + (size_t)(bcol + lr) * K + k0 + lc);
        __syncthreads();
        As[lc + 0][lr] = av.x; As[lc + 1][lr] = av.y; As[lc + 2][lr] = av.z; As[lc + 3][lr] = av.w;
        Bs[lc + 0][lr] = bv.x; Bs[lc + 1][lr] = bv.y; Bs[lc + 2][lr] = bv.z; Bs[lc + 3][lr] = bv.w;
        __syncthreads();
        #pragma unroll
        for (int kk = 0; kk < BK; ++kk) {
            float4 a4 = *(const float4*)(&As[kk][ty * 4]);
            float4 b4 = *(const float4*)(&Bs[kk][tx * 4]);
            float a[4] = {a4.x, a4.y, a4.z, a4.w};
            float b[4] = {b4.x, b4.y, b4.z, b4.w};
            #pragma unroll
            for (int i = 0; i < 4; ++i)
                #pragma unroll
                for (int j = 0; j < 4; ++j)
                    acc[i][j] = fmaf(a[i], b[j], acc[i][j]);
        }
    }
    #pragma unroll
    for (int i = 0; i < 4; ++i) {
        int r = brow + ty * 4 + i;
        if (r < NNODES) {
            float4 o = make_float4(acc[i][0], acc[i][1], acc[i][2], acc[i][3]);
            *(float4*)(C + (size_t)r * HC + bcol + tx * 4) = o;
        }
    }
}

// ---------------- per-node attention scalars e_src/e_dst ----------------

__global__ __launch_bounds__(256) void compute_e_kernel(const float* __restrict__ h,
                                                        const float* __restrict__ asrc,
                                                        const float* __restrict__ adst,
                                                        float* __restrict__ es,
                                                        float* __restrict__ ed) {
    int node = blockIdx.x * 4 + (threadIdx.x >> 6);
    if (node >= NNODES) return;
    int lane = threadIdx.x & 63;
    float4 hv = *(const float4*)(h + (size_t)node * HC + lane * 4);
    float4 a1 = *(const float4*)(asrc + lane * 4);
    float4 a2 = *(const float4*)(adst + lane * 4);
    float ps = hv.x * a1.x + hv.y * a1.y + hv.z * a1.z + hv.w * a1.w;
    float pd = hv.x * a2.x + hv.y * a2.y + hv.z * a2.z + hv.w * a2.w;
    #pragma unroll
    for (int o = 8; o > 0; o >>= 1) {   // reduce within each 16-lane head group
        ps += __shfl_down(ps, o, 16);
        pd += __shfl_down(pd, o, 16);
    }
    if ((lane & 15) == 0) {
        es[node * 4 + (lane >> 4)] = ps;
        ed[node * 4 + (lane >> 4)] = pd;
    }
}

// ---------------- 4 dst nodes per block, one wave each: softmax + gather ----------------

__global__ __launch_bounds__(256) void aggregate_kernel(const float* __restrict__ h,
                                                        const int* __restrict__ ssrc,
                                                        const int* __restrict__ off,
                                                        const float* __restrict__ es,
                                                        const float* __restrict__ ed,
                                                        const float* __restrict__ bias,
                                                        float* __restrict__ out,
                                                        int apply_elu) {
    int dst = blockIdx.x * 4 + (threadIdx.x >> 6);
    if (dst >= NNODES) return;
    int lane = threadIdx.x & 63;
    int s = off[dst], e = off[dst + 1];
    float4 ed4 = *(const float4*)(ed + dst * 4);
    // phase 1: per-head max logit over all incoming edges
    float m0 = -1e30f, m1 = -1e30f, m2 = -1e30f, m3 = -1e30f;
    for (int p = s + lane; p < e; p += 64) {
        int src = ssrc[p];
        float4 es4 = *(const float4*)(es + src * 4);
        float l0 = es4.x + ed4.x; l0 = l0 > 0.f ? l0 : 0.2f * l0;
        float l1 = es4.y + ed4.y; l1 = l1 > 0.f ? l1 : 0.2f * l1;
        float l2 = es4.z + ed4.z; l2 = l2 > 0.f ? l2 : 0.2f * l2;
        float l3 = es4.w + ed4.w; l3 = l3 > 0.f ? l3 : 0.2f * l3;
        m0 = fmaxf(m0, l0); m1 = fmaxf(m1, l1); m2 = fmaxf(m2, l2); m3 = fmaxf(m3, l3);
    }
    #pragma unroll
    for (int o = 32; o > 0; o >>= 1) {
        m0 = fmaxf(m0, __shfl_xor(m0, o));
        m1 = fmaxf(m1, __shfl_xor(m1, o));
        m2 = fmaxf(m2, __shfl_xor(m2, o));
        m3 = fmaxf(m3, __shfl_xor(m3, o));
    }
    int head = lane >> 4;
    float myM = (head == 0) ? m0 : (head == 1) ? m1 : (head == 2) ? m2 : m3;
    float edh = (head == 0) ? ed4.x : (head == 1) ? ed4.y : (head == 2) ? ed4.z : ed4.w;
    // phase 2: weighted sum; lane owns channels [lane*4, lane*4+4).
    // Unrolled x4 with independent accumulators for memory-level parallelism.
    float d0 = 0.f, d1 = 0.f, d2 = 0.f, d3 = 0.f;
    float4 a0 = make_float4(0.f, 0.f, 0.f, 0.f);
    float4 a1 = make_float4(0.f, 0.f, 0.f, 0.f);
    float4 a2 = make_float4(0.f, 0.f, 0.f, 0.f);
    float4 a3 = make_float4(0.f, 0.f, 0.f, 0.f);
    int p = s;
    for (; p + 4 <= e; p += 4) {
        int s0 = ssrc[p], s1 = ssrc[p + 1], s2 = ssrc[p + 2], s3 = ssrc[p + 3];
        float l0 = es[s0 * 4 + head] + edh;
        float l1 = es[s1 * 4 + head] + edh;
        float l2 = es[s2 * 4 + head] + edh;
        float l3 = es[s3 * 4 + head] + edh;
        float4 h0 = *(const float4*)(h + (size_t)s0 * HC + lane * 4);
        float4 h1 = *(const float4*)(h + (size_t)s1 * HC + lane * 4);
        float4 h2 = *(const float4*)(h + (size_t)s2 * HC + lane * 4);
        float4 h3 = *(const float4*)(h + (size_t)s3 * HC + lane * 4);
        l0 = l0 > 0.f ? l0 : 0.2f * l0;
        l1 = l1 > 0.f ? l1 : 0.2f * l1;
        l2 = l2 > 0.f ? l2 : 0.2f * l2;
        l3 = l3 > 0.f ? l3 : 0.2f * l3;
        float e0 = __expf(l0 - myM), e1 = __expf(l1 - myM);
        float e2 = __expf(l2 - myM), e3 = __expf(l3 - myM);
        d0 += e0; d1 += e1; d2 += e2; d3 += e3;
        a0.x += h0.x * e0; a0.y += h0.y * e0; a0.z += h0.z * e0; a0.w += h0.w * e0;
        a1.x += h1.x * e1; a1.y += h1.y * e1; a1.z += h1.z * e1; a1.w += h1.w * e1;
        a2.x += h2.x * e2; a2.y += h2.y * e2; a2.z += h2.z * e2; a2.w += h2.w * e2;
        a3.x += h3.x * e3; a3.y += h3.y * e3; a3.z += h3.z * e3; a3.w += h3.w * e3;
    }
    for (; p < e; ++p) {
        int s0 = ssrc[p];
        float l0 = es[s0 * 4 + head] + edh;
        l0 = l0 > 0.f ? l0 : 0.2f * l0;
        float e0 = __expf(l0 - myM);
        float4 h0 = *(const float4*)(h + (size_t)s0 * HC + lane * 4);
        d0 += e0;
        a0.x += h0.x * e0; a0.y += h0.y * e0; a0.z += h0.z * e0; a0.w += h0.w * e0;
    }
    float denom = (d0 + d1) + (d2 + d3);
    float inv = 1.f / (denom + 1e-16f);
    float4 b4 = *(const float4*)(bias + lane * 4);
    float o0 = ((a0.x + a1.x) + (a2.x + a3.x)) * inv + b4.x;
    float o1 = ((a0.y + a1.y) + (a2.y + a3.y)) * inv + b4.y;
    float o2 = ((a0.z + a1.z) + (a2.z + a3.z)) * inv + b4.z;
    float o3 = ((a0.w + a1.w) + (a2.w + a3.w)) * inv + b4.w;
    if (apply_elu) {
        o0 = o0 > 0.f ? o0 : expm1f(o0);
        o1 = o1 > 0.f ? o1 : expm1f(o1);
        o2 = o2 > 0.f ? o2 : expm1f(o2);
        o3 = o3 > 0.f ? o3 : expm1f(o3);
    }
    *(float4*)(out + (size_t)dst * HC + lane * 4) = make_float4(o0, o1, o2, o3);
}

// ---------------- graph boundaries on sorted batch (binary search) ----------------

__global__ void gbound_kernel(const int* __restrict__ batch, int* __restrict__ goff) {
    int g = blockIdx.x * blockDim.x + threadIdx.x;
    if (g > NGRAPH) return;
    int lo = 0, hi = NNODES;
    while (lo < hi) {
        int mid = (lo + hi) >> 1;
        if (batch[mid] < g) lo = mid + 1; else hi = mid;
    }
    goff[g] = lo;
}

// ---------------- atomic-free mean pool: block = (graph, 64-channel chunk) ----------------

__global__ __launch_bounds__(256) void pool_kernel(const float* __restrict__ hin,
                                                   const int* __restrict__ goff,
                                                   float* __restrict__ pool) {
    int g = blockIdx.x;
    int cb = blockIdx.y;               // channel block: 0..3
    int lane = threadIdx.x & 63;
    int wid = threadIdx.x >> 6;
    int c = cb * 64 + lane;
    int s = goff[g], e = goff[g + 1];
    float acc = 0.f;
    for (int n = s + wid; n < e; n += 4)
        acc += hin[(size_t)n * HC + c];
    __shared__ float part[4][64];
    part[wid][lane] = acc;
    __syncthreads();
    if (wid == 0) {
        float v = (part[0][lane] + part[1][lane]) + (part[2][lane] + part[3][lane]);
        float cntf = fmaxf((float)(e - s), 1.f);
        pool[g * HC + c] = v / cntf;
    }
}

// ---------------- final classifier: out[G,10] = pooled @ Wl^T + bl ----------------

__global__ __launch_bounds__(64) void final_kernel(const float* __restrict__ pool,
                                                   const float* __restrict__ Wl,
                                                   const float* __restrict__ bl,
                                                   float* __restrict__ out) {
    int g = blockIdx.x;
    int lane = threadIdx.x;
    float4 pv = *(const float4*)(pool + g * HC + lane * 4);
    float acc[NOUT];
    #pragma unroll
    for (int o = 0; o < NOUT; ++o) {
        float4 wv = *(const float4*)(Wl + o * HC + lane * 4);
        acc[o] = pv.x * wv.x + pv.y * wv.y + pv.z * wv.z + pv.w * wv.w;
    }
    #pragma unroll
    for (int s = 32; s > 0; s >>= 1)
        #pragma unroll
        for (int o = 0; o < NOUT; ++o)
            acc[o] += __shfl_xor(acc[o], s);
    if (lane == 0) {
        #pragma unroll
        for (int o = 0; o < NOUT; ++o)
            out[g * NOUT + o] = acc[o] + bl[o];
    }
}

// ---------------- launch ----------------

extern "C" void kernel_launch(void* const* d_in, const int* in_sizes, int n_in,
                              void* d_out, int out_size, void* d_ws, size_t ws_size,
                              hipStream_t stream) {
    (void)in_sizes; (void)n_in; (void)out_size; (void)ws_size;
    const float* x   = (const float*)d_in[0];
    const int*   ei  = (const int*)d_in[1];
    const int*   bat = (const int*)d_in[2];
    const float* W1  = (const float*)d_in[3];
    const float* as1 = (const float*)d_in[4];
    const float* ad1 = (const float*)d_in[5];
    const float* b1  = (const float*)d_in[6];
    const float* W2  = (const float*)d_in[7];
    const float* as2 = (const float*)d_in[8];
    const float* ad2 = (const float*)d_in[9];
    const float* b2  = (const float*)d_in[10];
    const float* W3  = (const float*)d_in[11];
    const float* as3 = (const float*)d_in[12];
    const float* ad3 = (const float*)d_in[13];
    const float* b3  = (const float*)d_in[14];
    const float* Wl  = (const float*)d_in[15];
    const float* bl  = (const float*)d_in[16];
    float* out = (float*)d_out;

    char* ws = (char*)d_ws;
    size_t p = 0;
    auto alloc = [&](size_t bytes) {
        size_t a = p;
        p += (bytes + 255) & ~(size_t)255;
        return a;
    };
    int*   off  = (int*)(ws + alloc((NNODES + 1) * 4));
    int*   deg  = (int*)(ws + alloc((size_t)NNODES * 4));
    int*   cur  = (int*)(ws + alloc((size_t)NNODES * 4));
    int*   ssrc = (int*)(ws + alloc((size_t)ETOT * 4));
    float* es   = (float*)(ws + alloc((size_t)NNODES * NHEAD * 4));
    float* ed   = (float*)(ws + alloc((size_t)NNODES * NHEAD * 4));
    float* B0v  = (float*)(ws + alloc((size_t)NNODES * HC * 4));
    float* B1v  = (float*)(ws + alloc((size_t)NNODES * HC * 4));
    float* pool = (float*)(ws + alloc((size_t)NGRAPH * HC * 4));
    int*   goff = (int*)(ws + alloc((size_t)(NGRAPH + 1) * 4));

    // zero deg+cur (contiguous)
    hipMemsetAsync(deg, 0, (size_t)((char*)ssrc - (char*)deg), stream);

    // counting sort of edges (incl. self-loops) by dst — reused by all 3 layers
    degree_kernel<<<(ETOT + 255) / 256, 256, 0, stream>>>(ei, deg);
    scan_kernel<<<1, 1024, 0, stream>>>(deg, off);
    scatter_kernel<<<(ETOT + 255) / 256, 256, 0, stream>>>(ei, off, cur, ssrc);
    gbound_kernel<<<1, 128, 0, stream>>>(bat, goff);

    dim3 ggrid((NNODES + BM - 1) / BM, HC / BN);
    int nblocks4 = (NNODES + 3) / 4;

    // layer 1
    gemm_nt<<<ggrid, 256, 0, stream>>>(x, W1, B0v, FIN);
    compute_e_kernel<<<nblocks4, 256, 0, stream>>>(B0v, as1, ad1, es, ed);
    aggregate_kernel<<<nblocks4, 256, 0, stream>>>(B0v, ssrc, off, es, ed, b1, B1v, 1);
    // layer 2
    gemm_nt<<<ggrid, 256, 0, stream>>>(B1v, W2, B0v, HC);
    compute_e_kernel<<<nblocks4, 256, 0, stream>>>(B0v, as2, ad2, es, ed);
    aggregate_kernel<<<nblocks4, 256, 0, stream>>>(B0v, ssrc, off, es, ed, b2, B1v, 1);
    // layer 3
    gemm_nt<<<ggrid, 256, 0, stream>>>(B1v, W3, B0v, HC);
    compute_e_kernel<<<nblocks4, 256, 0, stream>>>(B0v, as3, ad3, es, ed);
    aggregate_kernel<<<nblocks4, 256, 0, stream>>>(B0v, ssrc, off, es, ed, b3, B1v, 0);

    // pool + classify
    dim3 pgrid(NGRAPH, HC / 64);
    pool_kernel<<<pgrid, 256, 0, stream>>>(B1v, goff, pool);
    final_kernel<<<NGRAPH, 64, 0, stream>>>(pool, Wl, bl, out);
}

// Round 3
// 582.752 us; speedup vs baseline: 2.3995x; 1.6132x over previous
//
#include <hip/hip_runtime.h>
#include <hip/hip_bf16.h>
#include <math.h>

#define NNODES 50000
#define NEDGES 800000
#define NGRAPH 64
#define FIN 128
#define HC 256     // H * HID
#define NHEAD 4
#define NOUT 10
#define ETOT (NEDGES + NNODES)   // edges + self-loops

typedef unsigned short u16;
typedef __attribute__((ext_vector_type(8))) short short8;
typedef __attribute__((ext_vector_type(4))) float f32x4;

__device__ inline u16 f2b(float f) {
    union { float f; unsigned u; } v; v.f = f;
    unsigned r = v.u + 0x7FFF + ((v.u >> 16) & 1);   // RNE (finite values)
    return (u16)(r >> 16);
}
__device__ inline float b2f(u16 u) {
    union { unsigned u; float f; } v; v.u = ((unsigned)u) << 16; return v.f;
}

// ---------------- fp32 -> bf16 conversion (n multiple of 4) ----------------

__global__ void conv_kernel(const float* __restrict__ in, u16* __restrict__ out, int n) {
    int i = (blockIdx.x * blockDim.x + threadIdx.x) * 4;
    if (i >= n) return;
    float4 v = *(const float4*)(in + i);
    ushort4 o;
    o.x = f2b(v.x); o.y = f2b(v.y); o.z = f2b(v.z); o.w = f2b(v.w);
    *(ushort4*)(out + i) = o;
}

// ---------------- counting sort of edges by dst ----------------

__global__ void degree_kernel(const int* __restrict__ ei, int* __restrict__ deg) {
    int e = blockIdx.x * blockDim.x + threadIdx.x;
    if (e >= ETOT) return;
    int dst = (e < NEDGES) ? ei[NEDGES + e] : (e - NEDGES);
    atomicAdd(&deg[dst], 1);
}

__global__ __launch_bounds__(1024) void scan_kernel(const int* __restrict__ deg,
                                                    int* __restrict__ off) {
    __shared__ int wsum[16];
    int tid = threadIdx.x, lane = tid & 63, wid = tid >> 6;
    int carry = 0;
    for (int base = 0; base < NNODES; base += 1024) {
        int i = base + tid;
        int v = (i < NNODES) ? deg[i] : 0;
        int x = v;
        #pragma unroll
        for (int o = 1; o < 64; o <<= 1) {
            int t = __shfl_up(x, o);
            if (lane >= o) x += t;
        }
        if (lane == 63) wsum[wid] = x;
        __syncthreads();
        if (wid == 0 && lane < 16) {
            int w = wsum[lane];
            #pragma unroll
            for (int o = 1; o < 16; o <<= 1) {
                int t = __shfl_up(w, o, 16);
                if (lane >= o) w += t;
            }
            wsum[lane] = w;
        }
        __syncthreads();
        int wexcl = (wid == 0) ? 0 : wsum[wid - 1];
        if (i < NNODES) off[i] = carry + wexcl + (x - v);
        int total = wsum[15];
        __syncthreads();
        carry += total;
    }
    if (tid == 0) off[NNODES] = carry;
}

__global__ void scatter_kernel(const int* __restrict__ ei, const int* __restrict__ off,
                               int* __restrict__ cur, int* __restrict__ ssrc) {
    int e = blockIdx.x * blockDim.x + threadIdx.x;
    if (e >= ETOT) return;
    int src, dst;
    if (e < NEDGES) { src = ei[e]; dst = ei[NEDGES + e]; }
    else            { src = dst = e - NEDGES; }
    int pos = off[dst] + atomicAdd(&cur[dst], 1);
    ssrc[pos] = src;
}

// ---------------- bf16 MFMA GEMM: C[N,256] = A[N,K] @ B[256,K]^T ----------------
// 128x128 tile, 4 waves (each 64x64 = 4x4 of 16x16x32 MFMA), BK=32.

#define TBM 128
#define TBN 128
#define TBK 32
#define LDT 40   // padded LDS row stride (bf16 elems): 80B, 16B-aligned rows

__global__ __launch_bounds__(256) void gemm_mfma(const u16* __restrict__ A,
                                                 const u16* __restrict__ B,
                                                 u16* __restrict__ C, int K) {
    __shared__ u16 Als[TBM * LDT];
    __shared__ u16 Bls[TBN * LDT];
    int tid = threadIdx.x;
    int wave = tid >> 6, lane = tid & 63;
    int brow = blockIdx.x * TBM;
    int bcol = blockIdx.y * TBN;
    int m_base = (wave >> 1) * 64;
    int n_base = (wave & 1) * 64;
    int r0 = tid >> 2;             // 0..63
    int kc = (tid & 3) * 8;        // 0,8,16,24
    int lquad = lane >> 4, l16 = lane & 15;

    f32x4 acc[4][4] = {};

    for (int k0 = 0; k0 < K; k0 += TBK) {
        uint4 av0 = make_uint4(0, 0, 0, 0), av1 = make_uint4(0, 0, 0, 0);
        int gr0 = brow + r0, gr1 = brow + 64 + r0;
        if (gr0 < NNODES) av0 = *(const uint4*)(A + (size_t)gr0 * K + k0 + kc);
        if (gr1 < NNODES) av1 = *(const uint4*)(A + (size_t)gr1 * K + k0 + kc);
        uint4 bv0 = *(const uint4*)(B + (size_t)(bcol + r0) * K + k0 + kc);
        uint4 bv1 = *(const uint4*)(B + (size_t)(bcol + 64 + r0) * K + k0 + kc);
        __syncthreads();
        *(uint4*)(&Als[r0 * LDT + kc]) = av0;
        *(uint4*)(&Als[(64 + r0) * LDT + kc]) = av1;
        *(uint4*)(&Bls[r0 * LDT + kc]) = bv0;
        *(uint4*)(&Bls[(64 + r0) * LDT + kc]) = bv1;
        __syncthreads();
        short8 fa[4], fb[4];
        #pragma unroll
        for (int i = 0; i < 4; ++i) {
            fa[i] = *(const short8*)(&Als[(m_base + i * 16 + l16) * LDT + lquad * 8]);
            fb[i] = *(const short8*)(&Bls[(n_base + i * 16 + l16) * LDT + lquad * 8]);
        }
        #pragma unroll
        for (int i = 0; i < 4; ++i)
            #pragma unroll
            for (int j = 0; j < 4; ++j)
                acc[i][j] = __builtin_amdgcn_mfma_f32_16x16x32_bf16(fa[i], fb[j], acc[i][j], 0, 0, 0);
    }

    // C/D layout: col = lane&15, row = (lane>>4)*4 + reg   [m89/m91 verified]
    #pragma unroll
    for (int i = 0; i < 4; ++i) {
        int rbase = brow + m_base + i * 16 + lquad * 4;
        #pragma unroll
        for (int r = 0; r < 4; ++r) {
            int row = rbase + r;
            if (row < NNODES) {
                #pragma unroll
                for (int j = 0; j < 4; ++j)
                    C[(size_t)row * HC + bcol + n_base + j * 16 + l16] = f2b(acc[i][j][r]);
            }
        }
    }
}

// ---------------- per-node attention scalars e_src/e_dst (bf16 h) ----------------

__global__ __launch_bounds__(256) void compute_e_kernel(const u16* __restrict__ h,
                                                        const float* __restrict__ asrc,
                                                        const float* __restrict__ adst,
                                                        float* __restrict__ es,
                                                        float* __restrict__ ed) {
    int node = blockIdx.x * 4 + (threadIdx.x >> 6);
    if (node >= NNODES) return;
    int lane = threadIdx.x & 63;
    ushort4 hu = *(const ushort4*)(h + (size_t)node * HC + lane * 4);
    float h0 = b2f(hu.x), h1 = b2f(hu.y), h2 = b2f(hu.z), h3 = b2f(hu.w);
    float4 a1 = *(const float4*)(asrc + lane * 4);
    float4 a2 = *(const float4*)(adst + lane * 4);
    float ps = h0 * a1.x + h1 * a1.y + h2 * a1.z + h3 * a1.w;
    float pd = h0 * a2.x + h1 * a2.y + h2 * a2.z + h3 * a2.w;
    #pragma unroll
    for (int o = 8; o > 0; o >>= 1) {
        ps += __shfl_down(ps, o, 16);
        pd += __shfl_down(pd, o, 16);
    }
    if ((lane & 15) == 0) {
        es[node * 4 + (lane >> 4)] = ps;
        ed[node * 4 + (lane >> 4)] = pd;
    }
}

// ---------------- 4 dst nodes per block: softmax + bf16 gather -> bf16 out ----------------

__global__ __launch_bounds__(256) void aggregate_kernel(const u16* __restrict__ h,
                                                        const int* __restrict__ ssrc,
                                                        const int* __restrict__ off,
                                                        const float* __restrict__ es,
                                                        const float* __restrict__ ed,
                                                        const float* __restrict__ bias,
                                                        u16* __restrict__ out,
                                                        int apply_elu) {
    int dst = blockIdx.x * 4 + (threadIdx.x >> 6);
    if (dst >= NNODES) return;
    int lane = threadIdx.x & 63;
    int s = off[dst], e = off[dst + 1];
    float4 ed4 = *(const float4*)(ed + dst * 4);
    // phase 1: per-head max logit
    float m0 = -1e30f, m1 = -1e30f, m2 = -1e30f, m3 = -1e30f;
    for (int p = s + lane; p < e; p += 64) {
        int src = ssrc[p];
        float4 es4 = *(const float4*)(es + src * 4);
        float l0 = es4.x + ed4.x; l0 = l0 > 0.f ? l0 : 0.2f * l0;
        float l1 = es4.y + ed4.y; l1 = l1 > 0.f ? l1 : 0.2f * l1;
        float l2 = es4.z + ed4.z; l2 = l2 > 0.f ? l2 : 0.2f * l2;
        float l3 = es4.w + ed4.w; l3 = l3 > 0.f ? l3 : 0.2f * l3;
        m0 = fmaxf(m0, l0); m1 = fmaxf(m1, l1); m2 = fmaxf(m2, l2); m3 = fmaxf(m3, l3);
    }
    #pragma unroll
    for (int o = 32; o > 0; o >>= 1) {
        m0 = fmaxf(m0, __shfl_xor(m0, o));
        m1 = fmaxf(m1, __shfl_xor(m1, o));
        m2 = fmaxf(m2, __shfl_xor(m2, o));
        m3 = fmaxf(m3, __shfl_xor(m3, o));
    }
    int head = lane >> 4;
    float myM = (head == 0) ? m0 : (head == 1) ? m1 : (head == 2) ? m2 : m3;
    float edh = (head == 0) ? ed4.x : (head == 1) ? ed4.y : (head == 2) ? ed4.z : ed4.w;
    // phase 2: weighted sum; lane owns channels [lane*4, lane*4+4)
    float d0 = 0.f, d1 = 0.f, d2 = 0.f, d3 = 0.f;
    float4 a0 = make_float4(0.f, 0.f, 0.f, 0.f);
    float4 a1 = make_float4(0.f, 0.f, 0.f, 0.f);
    float4 a2 = make_float4(0.f, 0.f, 0.f, 0.f);
    float4 a3 = make_float4(0.f, 0.f, 0.f, 0.f);
    int p = s;
    for (; p + 4 <= e; p += 4) {
        int s0 = ssrc[p], s1 = ssrc[p + 1], s2 = ssrc[p + 2], s3 = ssrc[p + 3];
        float l0 = es[s0 * 4 + head] + edh;
        float l1 = es[s1 * 4 + head] + edh;
        float l2 = es[s2 * 4 + head] + edh;
        float l3 = es[s3 * 4 + head] + edh;
        ushort4 h0 = *(const ushort4*)(h + (size_t)s0 * HC + lane * 4);
        ushort4 h1 = *(const ushort4*)(h + (size_t)s1 * HC + lane * 4);
        ushort4 h2 = *(const ushort4*)(h + (size_t)s2 * HC + lane * 4);
        ushort4 h3 = *(const ushort4*)(h + (size_t)s3 * HC + lane * 4);
        l0 = l0 > 0.f ? l0 : 0.2f * l0;
        l1 = l1 > 0.f ? l1 : 0.2f * l1;
        l2 = l2 > 0.f ? l2 : 0.2f * l2;
        l3 = l3 > 0.f ? l3 : 0.2f * l3;
        float e0 = __expf(l0 - myM), e1 = __expf(l1 - myM);
        float e2 = __expf(l2 - myM), e3 = __expf(l3 - myM);
        d0 += e0; d1 += e1; d2 += e2; d3 += e3;
        a0.x += b2f(h0.x) * e0; a0.y += b2f(h0.y) * e0; a0.z += b2f(h0.z) * e0; a0.w += b2f(h0.w) * e0;
        a1.x += b2f(h1.x) * e1; a1.y += b2f(h1.y) * e1; a1.z += b2f(h1.z) * e1; a1.w += b2f(h1.w) * e1;
        a2.x += b2f(h2.x) * e2; a2.y += b2f(h2.y) * e2; a2.z += b2f(h2.z) * e2; a2.w += b2f(h2.w) * e2;
        a3.x += b2f(h3.x) * e3; a3.y += b2f(h3.y) * e3; a3.z += b2f(h3.z) * e3; a3.w += b2f(h3.w) * e3;
    }
    for (; p < e; ++p) {
        int s0 = ssrc[p];
        float l0 = es[s0 * 4 + head] + edh;
        l0 = l0 > 0.f ? l0 : 0.2f * l0;
        float e0 = __expf(l0 - myM);
        ushort4 h0 = *(const ushort4*)(h + (size_t)s0 * HC + lane * 4);
        d0 += e0;
        a0.x += b2f(h0.x) * e0; a0.y += b2f(h0.y) * e0; a0.z += b2f(h0.z) * e0; a0.w += b2f(h0.w) * e0;
    }
    float denom = (d0 + d1) + (d2 + d3);
    float inv = 1.f / (denom + 1e-16f);
    float4 b4 = *(const float4*)(bias + lane * 4);
    float o0 = ((a0.x + a1.x) + (a2.x + a3.x)) * inv + b4.x;
    float o1 = ((a0.y + a1.y) + (a2.y + a3.y)) * inv + b4.y;
    float o2 = ((a0.z + a1.z) + (a2.z + a3.z)) * inv + b4.z;
    float o3 = ((a0.w + a1.w) + (a2.w + a3.w)) * inv + b4.w;
    if (apply_elu) {
        o0 = o0 > 0.f ? o0 : expm1f(o0);
        o1 = o1 > 0.f ? o1 : expm1f(o1);
        o2 = o2 > 0.f ? o2 : expm1f(o2);
        o3 = o3 > 0.f ? o3 : expm1f(o3);
    }
    ushort4 ov;
    ov.x = f2b(o0); ov.y = f2b(o1); ov.z = f2b(o2); ov.w = f2b(o3);
    *(ushort4*)(out + (size_t)dst * HC + lane * 4) = ov;
}

// ---------------- graph boundaries on sorted batch ----------------

__global__ void gbound_kernel(const int* __restrict__ batch, int* __restrict__ goff) {
    int g = blockIdx.x * blockDim.x + threadIdx.x;
    if (g > NGRAPH) return;
    int lo = 0, hi = NNODES;
    while (lo < hi) {
        int mid = (lo + hi) >> 1;
        if (batch[mid] < g) lo = mid + 1; else hi = mid;
    }
    goff[g] = lo;
}

// ---------------- atomic-free mean pool (bf16 in) ----------------

__global__ __launch_bounds__(256) void pool_kernel(const u16* __restrict__ hin,
                                                   const int* __restrict__ goff,
                                                   float* __restrict__ pool) {
    int g = blockIdx.x;
    int cb = blockIdx.y;               // channel block: 0..3
    int lane = threadIdx.x & 63;
    int wid = threadIdx.x >> 6;
    int c = cb * 64 + lane;
    int s = goff[g], e = goff[g + 1];
    float acc = 0.f;
    for (int n = s + wid; n < e; n += 4)
        acc += b2f(hin[(size_t)n * HC + c]);
    __shared__ float part[4][64];
    part[wid][lane] = acc;
    __syncthreads();
    if (wid == 0) {
        float v = (part[0][lane] + part[1][lane]) + (part[2][lane] + part[3][lane]);
        float cntf = fmaxf((float)(e - s), 1.f);
        pool[g * HC + c] = v / cntf;
    }
}

// ---------------- final classifier ----------------

__global__ __launch_bounds__(64) void final_kernel(const float* __restrict__ pool,
                                                   const float* __restrict__ Wl,
                                                   const float* __restrict__ bl,
                                                   float* __restrict__ out) {
    int g = blockIdx.x;
    int lane = threadIdx.x;
    float4 pv = *(const float4*)(pool + g * HC + lane * 4);
    float acc[NOUT];
    #pragma unroll
    for (int o = 0; o < NOUT; ++o) {
        float4 wv = *(const float4*)(Wl + o * HC + lane * 4);
        acc[o] = pv.x * wv.x + pv.y * wv.y + pv.z * wv.z + pv.w * wv.w;
    }
    #pragma unroll
    for (int s = 32; s > 0; s >>= 1)
        #pragma unroll
        for (int o = 0; o < NOUT; ++o)
            acc[o] += __shfl_xor(acc[o], s);
    if (lane == 0) {
        #pragma unroll
        for (int o = 0; o < NOUT; ++o)
            out[g * NOUT + o] = acc[o] + bl[o];
    }
}

// ---------------- launch ----------------

extern "C" void kernel_launch(void* const* d_in, const int* in_sizes, int n_in,
                              void* d_out, int out_size, void* d_ws, size_t ws_size,
                              hipStream_t stream) {
    (void)in_sizes; (void)n_in; (void)out_size; (void)ws_size;
    const float* x   = (const float*)d_in[0];
    const int*   ei  = (const int*)d_in[1];
    const int*   bat = (const int*)d_in[2];
    const float* W1  = (const float*)d_in[3];
    const float* as1 = (const float*)d_in[4];
    const float* ad1 = (const float*)d_in[5];
    const float* b1  = (const float*)d_in[6];
    const float* W2  = (const float*)d_in[7];
    const float* as2 = (const float*)d_in[8];
    const float* ad2 = (const float*)d_in[9];
    const float* b2  = (const float*)d_in[10];
    const float* W3  = (const float*)d_in[11];
    const float* as3 = (const float*)d_in[12];
    const float* ad3 = (const float*)d_in[13];
    const float* b3  = (const float*)d_in[14];
    const float* Wl  = (const float*)d_in[15];
    const float* bl  = (const float*)d_in[16];
    float* out = (float*)d_out;

    char* ws = (char*)d_ws;
    size_t p = 0;
    auto alloc = [&](size_t bytes) {
        size_t a = p;
        p += (bytes + 255) & ~(size_t)255;
        return a;
    };
    int*   off  = (int*)(ws + alloc((NNODES + 1) * 4));
    int*   deg  = (int*)(ws + alloc((size_t)NNODES * 4));
    int*   cur  = (int*)(ws + alloc((size_t)NNODES * 4));
    int*   ssrc = (int*)(ws + alloc((size_t)ETOT * 4));
    float* es   = (float*)(ws + alloc((size_t)NNODES * NHEAD * 4));
    float* ed   = (float*)(ws + alloc((size_t)NNODES * NHEAD * 4));
    u16*   xb   = (u16*)(ws + alloc((size_t)NNODES * FIN * 2));
    u16*   w1b  = (u16*)(ws + alloc((size_t)HC * FIN * 2));
    u16*   w2b  = (u16*)(ws + alloc((size_t)HC * HC * 2));
    u16*   w3b  = (u16*)(ws + alloc((size_t)HC * HC * 2));
    u16*   Hb   = (u16*)(ws + alloc((size_t)NNODES * HC * 2));   // GEMM out (gather src)
    u16*   Ab   = (u16*)(ws + alloc((size_t)NNODES * HC * 2));   // aggregate out (next GEMM in)
    float* pool = (float*)(ws + alloc((size_t)NGRAPH * HC * 4));
    int*   goff = (int*)(ws + alloc((size_t)(NGRAPH + 1) * 4));

    // zero deg+cur (contiguous)
    hipMemsetAsync(deg, 0, (size_t)((char*)ssrc - (char*)deg), stream);

    // conversions to bf16
    conv_kernel<<<(NNODES * FIN / 4 + 255) / 256, 256, 0, stream>>>(x, xb, NNODES * FIN);
    conv_kernel<<<(HC * FIN / 4 + 255) / 256, 256, 0, stream>>>(W1, w1b, HC * FIN);
    conv_kernel<<<(HC * HC / 4 + 255) / 256, 256, 0, stream>>>(W2, w2b, HC * HC);
    conv_kernel<<<(HC * HC / 4 + 255) / 256, 256, 0, stream>>>(W3, w3b, HC * HC);

    // counting sort of edges by dst — reused by all 3 layers
    degree_kernel<<<(ETOT + 255) / 256, 256, 0, stream>>>(ei, deg);
    scan_kernel<<<1, 1024, 0, stream>>>(deg, off);
    scatter_kernel<<<(ETOT + 255) / 256, 256, 0, stream>>>(ei, off, cur, ssrc);
    gbound_kernel<<<1, 128, 0, stream>>>(bat, goff);

    dim3 ggrid((NNODES + TBM - 1) / TBM, HC / TBN);
    int nblocks4 = (NNODES + 3) / 4;

    // layer 1
    gemm_mfma<<<ggrid, 256, 0, stream>>>(xb, w1b, Hb, FIN);
    compute_e_kernel<<<nblocks4, 256, 0, stream>>>(Hb, as1, ad1, es, ed);
    aggregate_kernel<<<nblocks4, 256, 0, stream>>>(Hb, ssrc, off, es, ed, b1, Ab, 1);
    // layer 2
    gemm_mfma<<<ggrid, 256, 0, stream>>>(Ab, w2b, Hb, HC);
    compute_e_kernel<<<nblocks4, 256, 0, stream>>>(Hb, as2, ad2, es, ed);
    aggregate_kernel<<<nblocks4, 256, 0, stream>>>(Hb, ssrc, off, es, ed, b2, Ab, 1);
    // layer 3
    gemm_mfma<<<ggrid, 256, 0, stream>>>(Ab, w3b, Hb, HC);
    compute_e_kernel<<<nblocks4, 256, 0, stream>>>(Hb, as3, ad3, es, ed);
    aggregate_kernel<<<nblocks4, 256, 0, stream>>>(Hb, ssrc, off, es, ed, b3, Ab, 0);

    // pool + classify
    dim3 pgrid(NGRAPH, HC / 64);
    pool_kernel<<<pgrid, 256, 0, stream>>>(Ab, goff, pool);
    final_kernel<<<NGRAPH, 64, 0, stream>>>(pool, Wl, bl, out);
}